// Round 14
// baseline (174.870 us; speedup 1.0000x reference)
//
#include <hip/hip_runtime.h>
#include <hip/hip_bf16.h>

#define DEVI __device__ __forceinline__

typedef __attribute__((ext_vector_type(4))) float f32x4;
typedef __attribute__((ext_vector_type(16))) float f32x16;
typedef __attribute__((ext_vector_type(8))) short bf16x8;
typedef __attribute__((ext_vector_type(4))) short bf16x4;
typedef __attribute__((ext_vector_type(4))) int i32x4;

constexpr int Bb = 4, Tt = 2048, Cc = 1024, Hh = 16, HDd = 64;
constexpr int Mm = Bb * Tt; // 8192

// ---- bf16 helpers ----
DEVI short f2bf(float f) {
    union { float f; unsigned u; } x; x.f = f;
    unsigned r = x.u + 0x7FFFu + ((x.u >> 16) & 1u); // round-nearest-even
    return (short)(r >> 16);
}

DEVI float bf2f(short s) {
    return __builtin_bit_cast(float, (unsigned)((unsigned short)s) << 16);
}

DEVI int cvtpk(float lo, float hi) { // packs {bf16(lo), bf16(hi)}, lo in low 16
    int r;
    asm("v_cvt_pk_bf16_f32 %0, %1, %2" : "=v"(r) : "v"(lo), "v"(hi));
    return r;
}

// raw v_exp_f32 (library exp2f w/o fast-math is a ~6-inst guarded sequence)
DEVI float fexp2(float x) { return __builtin_amdgcn_exp2f(x); }

DEVI void gload_lds16(const void* g, void* l) {
    __builtin_amdgcn_global_load_lds(
        (const __attribute__((address_space(1))) unsigned int*)g,
        (__attribute__((address_space(3))) unsigned int*)l, 16, 0, 0);
}

// ---------------- fp32 -> bf16 conversion ----------------
__global__ void cvt_kernel(const float* __restrict__ s, short* __restrict__ d, int n8) {
    int i = blockIdx.x * 256 + threadIdx.x;
    if (i < n8) {
        const float4* sp = (const float4*)s;
        float4 a = sp[2 * i], b = sp[2 * i + 1];
        short tmp[8];
        tmp[0] = f2bf(a.x); tmp[1] = f2bf(a.y); tmp[2] = f2bf(a.z); tmp[3] = f2bf(a.w);
        tmp[4] = f2bf(b.x); tmp[5] = f2bf(b.y); tmp[6] = f2bf(b.z); tmp[7] = f2bf(b.w);
        *(bf16x8*)(d + 8 * (size_t)i) = *(bf16x8*)tmp;
    }
}

// 4 weight matrices in one launch; blockIdx.y selects.
__global__ void cvtw_kernel(const float* __restrict__ w0, const float* __restrict__ w1,
                            const float* __restrict__ w2, const float* __restrict__ w3,
                            short* __restrict__ d0, short* __restrict__ d1,
                            short* __restrict__ d2, short* __restrict__ d3) {
    const int sel = blockIdx.y;
    const float* s = sel == 0 ? w0 : sel == 1 ? w1 : sel == 2 ? w2 : w3;
    short* d = sel == 0 ? d0 : sel == 1 ? d1 : sel == 2 ? d2 : d3;
    const int i = blockIdx.x * 256 + threadIdx.x;
    const float4* sp = (const float4*)s;
    float4 a = sp[2 * i], b = sp[2 * i + 1];
    short tmp[8];
    tmp[0] = f2bf(a.x); tmp[1] = f2bf(a.y); tmp[2] = f2bf(a.z); tmp[3] = f2bf(a.w);
    tmp[4] = f2bf(b.x); tmp[5] = f2bf(b.y); tmp[6] = f2bf(b.z); tmp[7] = f2bf(b.w);
    *(bf16x8*)(d + 8 * (size_t)i) = *(bf16x8*)tmp;
}

// ---------------- GEMM core (128x128 tile, BK=64) ----------------
struct GemmAcc { f32x4 acc[4][4]; };

DEVI void gemm_core(const short* __restrict__ A, const short* __restrict__ Bw,
                    int Kdim, int bm, int bn, int tid,
                    short (*As)[64], short (*Bs)[64], GemmAcc& G)
{
    const int lane = tid & 63, wid = tid >> 6;
    const int wr = wid >> 1, wc = wid & 1;
    const int lrow = lane >> 3;
    const int lcol = (lane & 7) * 8;

    for (int k0 = 0; k0 < Kdim; k0 += 64) {
        #pragma unroll
        for (int c = 0; c < 4; ++c) {
            const int chunk = wid * 4 + c;
            const int row = chunk * 8 + lrow;
            gload_lds16(A  + (size_t)(bm + row) * Kdim + k0 + lcol, &As[chunk * 8][0]);
            gload_lds16(Bw + (size_t)(bn + row) * Kdim + k0 + lcol, &Bs[chunk * 8][0]);
        }
        __syncthreads();
        const int rr = lane & 15;
        #pragma unroll
        for (int kk = 0; kk < 64; kk += 32) {
            const int koff = kk + (lane >> 4) * 8;
            bf16x8 af[4], bfr[4];
            #pragma unroll
            for (int m_ = 0; m_ < 4; ++m_)
                af[m_] = *(const bf16x8*)&As[wr * 64 + m_ * 16 + rr][koff];
            #pragma unroll
            for (int n_ = 0; n_ < 4; ++n_)
                bfr[n_] = *(const bf16x8*)&Bs[wc * 64 + n_ * 16 + rr][koff];
            #pragma unroll
            for (int m_ = 0; m_ < 4; ++m_)
                #pragma unroll
                for (int n_ = 0; n_ < 4; ++n_)
                    G.acc[m_][n_] = __builtin_amdgcn_mfma_f32_16x16x32_bf16(
                        af[m_], bfr[n_], G.acc[m_][n_], 0, 0, 0);
        }
        __syncthreads();
    }
}

// Fused Q/K/V projection: grid (M/128, 24); blockIdx.y>>3 selects section.
__global__ __launch_bounds__(256, 2)
void gemm_qkv(const short* __restrict__ A,
              const short* __restrict__ Wq, const short* __restrict__ Wk,
              const short* __restrict__ Wv,
              const float* __restrict__ bq, const float* __restrict__ bk,
              const float* __restrict__ bv,
              short* __restrict__ Qo, short* __restrict__ Ko, short* __restrict__ Vto,
              float sq)
{
    __shared__ __align__(16) short As[128][64];
    __shared__ __align__(16) short Bs[128][64];
    const int sec = blockIdx.y >> 3;
    const int bn = (blockIdx.y & 7) * 128;
    const int bm = blockIdx.x * 128;
    const short* Bw = sec == 0 ? Wq : sec == 1 ? Wk : Wv;
    const float* bias = sec == 0 ? bq : sec == 1 ? bk : bv;
    const float scale = sec == 0 ? sq : 1.0f;

    GemmAcc G = {};
    gemm_core(A, Bw, Cc, bm, bn, threadIdx.x, As, Bs, G);

    const int lane = threadIdx.x & 63, wid = threadIdx.x >> 6;
    const int wr = wid >> 1, wc = wid & 1;
    const int cidx = lane & 15;
    const int r4 = (lane >> 4) * 4;
    #pragma unroll
    for (int n_ = 0; n_ < 4; ++n_) {
        const int col = bn + wc * 64 + n_ * 16 + cidx;
        const float bv_ = bias[col];
        #pragma unroll
        for (int m_ = 0; m_ < 4; ++m_) {
            const int rowb = bm + wr * 64 + m_ * 16 + r4;
            if (sec == 2) {
                // transposed V: Vt[((b*16+h)*64 + d)][t]
                const int h_ = col >> 6, d_ = col & 63;
                const int b_ = rowb >> 11, t_ = rowb & 2047;
                short tmp[4];
                #pragma unroll
                for (int i = 0; i < 4; ++i) tmp[i] = f2bf((G.acc[m_][n_][i] + bv_));
                *(bf16x4*)(Vto + ((size_t)((b_ * Hh + h_) * HDd + d_)) * Tt + t_) = *(bf16x4*)tmp;
            } else {
                short* C = sec == 0 ? Qo : Ko;
                #pragma unroll
                for (int i = 0; i < 4; ++i)
                    C[(size_t)(rowb + i) * Cc + col] = f2bf((G.acc[m_][n_][i] + bv_) * scale);
            }
        }
    }
}

// Output projection: fp32 out.
__global__ __launch_bounds__(256, 2)
void gemm_out(const short* __restrict__ A, const short* __restrict__ Bw,
              const float* __restrict__ bias, float* __restrict__ Cout)
{
    __shared__ __align__(16) short As[128][64];
    __shared__ __align__(16) short Bs[128][64];
    const int bm = blockIdx.x * 128;
    const int bn = blockIdx.y * 128;
    GemmAcc G = {};
    gemm_core(A, Bw, Cc, bm, bn, threadIdx.x, As, Bs, G);

    const int lane = threadIdx.x & 63, wid = threadIdx.x >> 6;
    const int wr = wid >> 1, wc = wid & 1;
    const int cidx = lane & 15;
    const int r4 = (lane >> 4) * 4;
    #pragma unroll
    for (int n_ = 0; n_ < 4; ++n_) {
        const int col = bn + wc * 64 + n_ * 16 + cidx;
        const float bv_ = bias[col];
        #pragma unroll
        for (int m_ = 0; m_ < 4; ++m_) {
            const int rowb = bm + wr * 64 + m_ * 16 + r4;
            #pragma unroll
            for (int i = 0; i < 4; ++i)
                Cout[(size_t)(rowb + i) * Cc + col] = G.acc[m_][n_][i] + bv_;
        }
    }
}

// ---------------- Flash attention (causal, 32x32 MFMA, in-register P) ----------------
template<bool DIAG>
DEVI void attn_tile(int kv0, const short (*Kt)[64], const short (*Vd)[64],
                    const bf16x8 (&qf)[4], int lane, int qrow,
                    f32x16 (&oacc)[2], float &mrow, float &lsum)
{
    const int q31 = lane & 31;
    const int hi  = lane >> 5;

    f32x16 sacc[2] = {};
    __builtin_amdgcn_s_setprio(1);
    #pragma unroll
    for (int ks = 0; ks < 4; ++ks) {
        #pragma unroll
        for (int nb = 0; nb < 2; ++nb) {
            const int row = nb * 32 + q31;  // A-operand row = kv
            bf16x8 kf = *(const bf16x8*)&Kt[row][(((ks << 1) | hi) ^ (row & 7)) * 8];
            sacc[nb] = __builtin_amdgcn_mfma_f32_32x32x16_bf16(kf, qf[ks], sacc[nb], 0, 0, 0);
        }
    }
    __builtin_amdgcn_s_setprio(0);

    if (DIAG) {
        #pragma unroll
        for (int nb = 0; nb < 2; ++nb)
            #pragma unroll
            for (int r = 0; r < 16; ++r) {
                const int kv = kv0 + nb * 32 + (r & 3) + 8 * (r >> 2) + 4 * hi;
                if (kv > qrow) sacc[nb][r] = -1e30f;
            }
    }

    // row max: pairwise tree, depth 5, then one cross-half swap
    float tm[16];
    #pragma unroll
    for (int r = 0; r < 16; ++r) tm[r] = fmaxf(sacc[0][r], sacc[1][r]);
    #pragma unroll
    for (int st = 8; st >= 1; st >>= 1)
        #pragma unroll
        for (int r = 0; r < st; ++r) tm[r] = fmaxf(tm[r], tm[r + st]);
    const float pmax = fmaxf(tm[0], __shfl_xor(tm[0], 32, 64));

    if (!__all(pmax <= mrow + 8.0f)) {          // defer-max: rescale rarely
        const float mnew = fmaxf(mrow, pmax);
        const float alpha = fexp2(mrow - mnew);
        mrow = mnew;
        lsum *= alpha;
        #pragma unroll
        for (int r = 0; r < 16; ++r) {
            const float ar = __shfl(alpha, (r & 3) + 8 * (r >> 2) + 4 * hi, 32);
            oacc[0][r] *= ar;
            oacc[1][r] *= ar;
        }
    }

    #pragma unroll
    for (int nb = 0; nb < 2; ++nb)
        #pragma unroll
        for (int r = 0; r < 16; ++r)
            sacc[nb][r] = fexp2(sacc[nb][r] - mrow);
    float ps[16];
    #pragma unroll
    for (int r = 0; r < 16; ++r) ps[r] = sacc[0][r] + sacc[1][r];
    #pragma unroll
    for (int st = 8; st >= 1; st >>= 1)
        #pragma unroll
        for (int r = 0; r < st; ++r) ps[r] += ps[r + st];
    lsum += ps[0];

    // PV with in-register P (cvt_pk + permlane32_swap)
    #pragma unroll
    for (int ks = 0; ks < 4; ++ks) {
        const int n = ks >> 1, b8 = (ks & 1) * 8;
        int x0 = cvtpk(sacc[n][b8 + 0], sacc[n][b8 + 1]);
        int x1 = cvtpk(sacc[n][b8 + 2], sacc[n][b8 + 3]);
        int y0 = cvtpk(sacc[n][b8 + 4], sacc[n][b8 + 5]);
        int y1 = cvtpk(sacc[n][b8 + 6], sacc[n][b8 + 7]);
        asm volatile("v_permlane32_swap_b32 %0, %1" : "+v"(x0), "+v"(y0));
        asm volatile("v_permlane32_swap_b32 %0, %1" : "+v"(x1), "+v"(y1));
        i32x4 w; w.x = x0; w.y = x1; w.z = y0; w.w = y1;
        const bf16x8 pav = __builtin_bit_cast(bf16x8, w);
        __builtin_amdgcn_s_setprio(1);
        #pragma unroll
        for (int nb = 0; nb < 2; ++nb) {
            const int row = nb * 32 + q31;  // B-operand col = d
            bf16x8 vf = *(const bf16x8*)&Vd[row][(((ks << 1) | hi) ^ (row & 7)) * 8];
            oacc[nb] = __builtin_amdgcn_mfma_f32_32x32x16_bf16(pav, vf, oacc[nb], 0, 0, 0);
        }
        __builtin_amdgcn_s_setprio(0);
    }
}

// KV range [ktLo, ktHi) of q-tile qt. If OPpart==nullptr: full pass, write
// normalized O. Else: write unnormalized bf16 partial + per-row m/l (fp32).
DEVI void attn_range(int qt, int ktLo, int ktHi,
                     const short* __restrict__ Q, short* __restrict__ O,
                     short* __restrict__ OPpart, float* __restrict__ MP,
                     float* __restrict__ LP,
                     const short* kbase, const short* vbase, size_t baseRow, int h,
                     int lane, int wid, short (*Kb)[64][64], short (*Vb)[64][64])
{
    const int q0 = qt * 128;
    const int q31 = lane & 31;
    const int hi = lane >> 5;
    const int qrow = q0 + wid * 32 + q31;
    const int NT = 2 * qt + 2;

    const short* qptr = Q + (baseRow + qrow) * Cc + h * HDd + hi * 8;
    bf16x8 qf[4];
    #pragma unroll
    for (int ks = 0; ks < 4; ++ks) qf[ks] = *(const bf16x8*)(qptr + ks * 16);

    f32x16 oacc[2] = {};
    float mrow = -1e30f, lsum = 0.f;

    auto STAGE = [&](int bsel, int kv0) {
        #pragma unroll
        for (int j = 0; j < 2; ++j) {
            const int r0 = wid * 16 + j * 8;
            const int row = r0 + (lane >> 3);
            const int sc = ((lane & 7) ^ (row & 7)) * 8;   // source-side chunk swizzle
            gload_lds16(kbase + (size_t)(kv0 + row) * Cc + sc, &Kb[bsel][r0][0]);
            gload_lds16(vbase + (size_t)row * Tt + kv0 + sc, &Vb[bsel][r0][0]);
        }
    };

    STAGE(0, ktLo * 64);
    int buf = 0;
    for (int kt = ktLo; kt < ktHi; ++kt) {
        if (kt + 1 < ktHi) {
            STAGE(buf ^ 1, (kt + 1) * 64);                   // +4 in flight
            asm volatile("s_waitcnt vmcnt(4)" ::: "memory");
        } else {
            asm volatile("s_waitcnt vmcnt(0)" ::: "memory");
        }
        __builtin_amdgcn_s_barrier();
        __builtin_amdgcn_sched_barrier(0);
        if (kt >= NT - 2)   // diagonal band (chunk 0 of a split never reaches it)
            attn_tile<true >(kt * 64, Kb[buf], Vb[buf], qf, lane, qrow, oacc, mrow, lsum);
        else
            attn_tile<false>(kt * 64, Kb[buf], Vb[buf], qf, lane, qrow, oacc, mrow, lsum);
        __builtin_amdgcn_s_barrier();
        buf ^= 1;
    }

    lsum += __shfl_xor(lsum, 32, 64);   // total over this KV range, per q=q31

    if (OPpart == nullptr) {
        #pragma unroll
        for (int r = 0; r < 16; ++r) {
            const int crow = (r & 3) + 8 * (r >> 2) + 4 * hi;
            const float ri = __builtin_amdgcn_rcpf(__shfl(lsum, crow, 32));
            const size_t rb = (baseRow + q0 + wid * 32 + crow) * Cc + h * HDd + q31;
            O[rb]      = f2bf(oacc[0][r] * ri);
            O[rb + 32] = f2bf(oacc[1][r] * ri);
        }
    } else {
        // unnormalized partial: OPpart[row 0..127][d 0..63] bf16; m/l per row.
        #pragma unroll
        for (int r = 0; r < 16; ++r) {
            const int crow = (r & 3) + 8 * (r >> 2) + 4 * hi;
            const int row = wid * 32 + crow;
            OPpart[row * 64 + q31]      = f2bf(oacc[0][r]);
            OPpart[row * 64 + 32 + q31] = f2bf(oacc[1][r]);
        }
        if (hi == 0) {           // lanes 0..31: one per q-row of this wave
            MP[wid * 32 + q31] = mrow;
            LP[wid * 32 + q31] = lsum;
        }
    }
}

// Job table: 24 jobs/bh in DESCENDING duration (fine-grained LPT).
// qt 0..7 unsplit (NT=2qt+2 tiles); qt 8..15 split into 2 chunks of qt+1 tiles.
__device__ const signed char JQT[24] = {7,15,15,14,14,6,13,13,12,12,5,11,11,10,10,4,9,9,8,8,3,2,1,0};
__device__ const signed char JCH[24] = {-1,0,1,0,1,-1,0,1,0,1,-1,0,1,0,1,-1,0,1,0,1,-1,-1,-1,-1};

// grid 1536 = [job:24][bh_hi:8][bh_lo:8]; bid%8 -> bh%8 keeps XCD affinity.
__global__ __launch_bounds__(256, 3)
void attn_kernel(const short* __restrict__ Q, const short* __restrict__ K,
                 const short* __restrict__ Vt, short* __restrict__ O,
                 short* __restrict__ OP, float* __restrict__ MP, float* __restrict__ LP)
{
    const int bid = blockIdx.x;
    const int bh = (bid & 7) + 8 * ((bid >> 3) & 7);
    const int job = bid >> 6;
    const int qt = JQT[job];
    const int ch = JCH[job];
    const int b = bh >> 4, h = bh & 15;
    const size_t baseRow = (size_t)b * Tt;
    const int tid = threadIdx.x, lane = tid & 63, wid = tid >> 6;

    __shared__ __align__(16) short Kb[2][64][64];
    __shared__ __align__(16) short Vb[2][64][64];

    const short* kbase = K + baseRow * Cc + h * HDd;
    const short* vbase = Vt + (size_t)bh * HDd * Tt;

    if (ch < 0) {
        attn_range(qt, 0, 2 * qt + 2, Q, O, nullptr, nullptr, nullptr,
                   kbase, vbase, baseRow, h, lane, wid, Kb, Vb);
    } else {
        const int qs = qt - 8;
        const int pbase = (bh * 8 + qs) * 2 + ch;
        const int ktLo = ch == 0 ? 0 : qt + 1;
        const int ktHi = ch == 0 ? qt + 1 : 2 * qt + 2;
        attn_range(qt, ktLo, ktHi, Q, O,
                   OP + (size_t)pbase * 128 * 64, MP + pbase * 128, LP + pbase * 128,
                   kbase, vbase, baseRow, h, lane, wid, Kb, Vb);
    }
}

// Merge the two chunks of each split (bh, qt>=8) block. grid 512 = bh*8+qs.
__global__ __launch_bounds__(256, 8)
void attn_merge(const short* __restrict__ OP, const float* __restrict__ MP,
                const float* __restrict__ LP, short* __restrict__ O)
{
    const int g = blockIdx.x;            // bh*8 + qs
    const int bh = g >> 3, qs = g & 7;
    const int qt = qs + 8;
    const int b = bh >> 4, h = bh & 15;
    const int tid = threadIdx.x;
    const int q = tid >> 1;
    const int dhalf = (tid & 1) * 32;

    const size_t i0 = ((size_t)g * 2 + 0) * 128 + q;
    const size_t i1 = ((size_t)g * 2 + 1) * 128 + q;
    const float m0 = MP[i0], m1 = MP[i1];
    const float l0 = LP[i0], l1 = LP[i1];
    const float m = fmaxf(m0, m1);
    float w0 = fexp2(m0 - m), w1 = fexp2(m1 - m);
    const float ri = __builtin_amdgcn_rcpf(l0 * w0 + l1 * w1);
    w0 *= ri; w1 *= ri;

    const short* p0 = OP + i0 * 64 + dhalf;
    const short* p1 = OP + i1 * 64 + dhalf;
    short* po = O + ((size_t)b * Tt + qt * 128 + q) * Cc + h * HDd + dhalf;
    #pragma unroll
    for (int j = 0; j < 32; j += 8) {
        bf16x8 a = *(const bf16x8*)(p0 + j);
        bf16x8 c = *(const bf16x8*)(p1 + j);
        short tmp[8];
        #pragma unroll
        for (int e = 0; e < 8; ++e)
            tmp[e] = f2bf(bf2f(((short*)&a)[e]) * w0 + bf2f(((short*)&c)[e]) * w1);
        *(bf16x8*)(po + j) = *(bf16x8*)tmp;
    }
}

// ---------------- host ----------------
extern "C" void kernel_launch(void* const* d_in, const int* in_sizes, int n_in,
                              void* d_out, int out_size, void* d_ws, size_t ws_size,
                              hipStream_t stream) {
    (void)in_sizes; (void)n_in; (void)out_size; (void)ws_size;
    const float* x  = (const float*)d_in[0];
    const float* Wq = (const float*)d_in[1];
    const float* bq = (const float*)d_in[2];
    const float* Wk = (const float*)d_in[3];
    const float* bk = (const float*)d_in[4];
    const float* Wv = (const float*)d_in[5];
    const float* bv = (const float*)d_in[6];
    const float* Wo = (const float*)d_in[7];
    const float* bo = (const float*)d_in[8];
    float* out = (float*)d_out;

    short* ws  = (short*)d_ws;
    short* xb  = ws;
    short* wqb = xb  + (size_t)Mm * Cc;
    short* wkb = wqb + (size_t)Cc * Cc;
    short* wvb = wkb + (size_t)Cc * Cc;
    short* wob = wvb + (size_t)Cc * Cc;
    short* Qb  = wob + (size_t)Cc * Cc;
    short* Kbg = Qb  + (size_t)Mm * Cc;
    short* Vtb = Kbg + (size_t)Mm * Cc;  // V written pre-transposed by the QKV GEMM
    short* Ob  = Vtb + (size_t)Mm * Cc;

    // During attn, xb/wqb/wkb are dead -> reuse for split-KV partials.
    short* OPart = xb;                   // 64*8*2*128*64 = 8.4M shorts == |xb|
    float* MPart = (float*)wqb;          // 131072 floats (wqb = 2 MB)
    float* LPart = (float*)wkb;          // 131072 floats

    const int nx8 = Mm * Cc / 8;
    const int nw8 = Cc * Cc / 8;
    cvt_kernel<<<(nx8 + 255) / 256, 256, 0, stream>>>(x, xb, nx8);
    cvtw_kernel<<<dim3(nw8 / 256, 4), 256, 0, stream>>>(Wq, Wk, Wv, Wo, wqb, wkb, wvb, wob);

    const float SCL = 0.125f * 1.44269504088896f;  // 1/sqrt(HD) * log2(e), folded into Q
    gemm_qkv<<<dim3(Mm / 128, 24), 256, 0, stream>>>(xb, wqb, wkb, wvb, bq, bk, bv,
                                                     Qb, Kbg, Vtb, SCL);

    attn_kernel<<<dim3(24 * 64), 256, 0, stream>>>(Qb, Kbg, Vtb, Ob, OPart, MPart, LPart);
    attn_merge<<<dim3(512), 256, 0, stream>>>(OPart, MPart, LPart, Ob);

    gemm_out<<<dim3(Mm / 128, Cc / 128), 256, 0, stream>>>(Ob, wob, bo, out);
}

// Round 15
// 167.241 us; speedup vs baseline: 1.0456x; 1.0456x over previous
//
#include <hip/hip_runtime.h>
#include <hip/hip_bf16.h>

#define DEVI __device__ __forceinline__

typedef __attribute__((ext_vector_type(4))) float f32x4;
typedef __attribute__((ext_vector_type(16))) float f32x16;
typedef __attribute__((ext_vector_type(8))) short bf16x8;
typedef __attribute__((ext_vector_type(4))) short bf16x4;
typedef __attribute__((ext_vector_type(4))) int i32x4;

constexpr int Bb = 4, Tt = 2048, Cc = 1024, Hh = 16, HDd = 64;
constexpr int Mm = Bb * Tt; // 8192

// ---- bf16 helpers ----
DEVI short f2bf(float f) {
    union { float f; unsigned u; } x; x.f = f;
    unsigned r = x.u + 0x7FFFu + ((x.u >> 16) & 1u); // round-nearest-even
    return (short)(r >> 16);
}

DEVI int cvtpk(float lo, float hi) { // packs {bf16(lo), bf16(hi)}, lo in low 16
    int r;
    asm("v_cvt_pk_bf16_f32 %0, %1, %2" : "=v"(r) : "v"(lo), "v"(hi));
    return r;
}

// raw v_exp_f32 (library exp2f w/o fast-math is a ~6-inst guarded sequence)
DEVI float fexp2(float x) { return __builtin_amdgcn_exp2f(x); }

DEVI void gload_lds16(const void* g, void* l) {
    __builtin_amdgcn_global_load_lds(
        (const __attribute__((address_space(1))) unsigned int*)g,
        (__attribute__((address_space(3))) unsigned int*)l, 16, 0, 0);
}

// ---------------- fp32 -> bf16 conversion ----------------
__global__ void cvt_kernel(const float* __restrict__ s, short* __restrict__ d, int n8) {
    int i = blockIdx.x * 256 + threadIdx.x;
    if (i < n8) {
        const float4* sp = (const float4*)s;
        float4 a = sp[2 * i], b = sp[2 * i + 1];
        short tmp[8];
        tmp[0] = f2bf(a.x); tmp[1] = f2bf(a.y); tmp[2] = f2bf(a.z); tmp[3] = f2bf(a.w);
        tmp[4] = f2bf(b.x); tmp[5] = f2bf(b.y); tmp[6] = f2bf(b.z); tmp[7] = f2bf(b.w);
        *(bf16x8*)(d + 8 * (size_t)i) = *(bf16x8*)tmp;
    }
}

// 4 weight matrices in one launch; blockIdx.y selects.
__global__ void cvtw_kernel(const float* __restrict__ w0, const float* __restrict__ w1,
                            const float* __restrict__ w2, const float* __restrict__ w3,
                            short* __restrict__ d0, short* __restrict__ d1,
                            short* __restrict__ d2, short* __restrict__ d3) {
    const int sel = blockIdx.y;
    const float* s = sel == 0 ? w0 : sel == 1 ? w1 : sel == 2 ? w2 : w3;
    short* d = sel == 0 ? d0 : sel == 1 ? d1 : sel == 2 ? d2 : d3;
    const int i = blockIdx.x * 256 + threadIdx.x;
    const float4* sp = (const float4*)s;
    float4 a = sp[2 * i], b = sp[2 * i + 1];
    short tmp[8];
    tmp[0] = f2bf(a.x); tmp[1] = f2bf(a.y); tmp[2] = f2bf(a.z); tmp[3] = f2bf(a.w);
    tmp[4] = f2bf(b.x); tmp[5] = f2bf(b.y); tmp[6] = f2bf(b.z); tmp[7] = f2bf(b.w);
    *(bf16x8*)(d + 8 * (size_t)i) = *(bf16x8*)tmp;
}

// ---------------- GEMM core (128x128 tile, BK=64) ----------------
struct GemmAcc { f32x4 acc[4][4]; };

DEVI void gemm_core(const short* __restrict__ A, const short* __restrict__ Bw,
                    int Kdim, int bm, int bn, int tid,
                    short (*As)[64], short (*Bs)[64], GemmAcc& G)
{
    const int lane = tid & 63, wid = tid >> 6;
    const int wr = wid >> 1, wc = wid & 1;
    const int lrow = lane >> 3;
    const int lcol = (lane & 7) * 8;

    for (int k0 = 0; k0 < Kdim; k0 += 64) {
        #pragma unroll
        for (int c = 0; c < 4; ++c) {
            const int chunk = wid * 4 + c;
            const int row = chunk * 8 + lrow;
            gload_lds16(A  + (size_t)(bm + row) * Kdim + k0 + lcol, &As[chunk * 8][0]);
            gload_lds16(Bw + (size_t)(bn + row) * Kdim + k0 + lcol, &Bs[chunk * 8][0]);
        }
        __syncthreads();
        const int rr = lane & 15;
        #pragma unroll
        for (int kk = 0; kk < 64; kk += 32) {
            const int koff = kk + (lane >> 4) * 8;
            bf16x8 af[4], bfr[4];
            #pragma unroll
            for (int m_ = 0; m_ < 4; ++m_)
                af[m_] = *(const bf16x8*)&As[wr * 64 + m_ * 16 + rr][koff];
            #pragma unroll
            for (int n_ = 0; n_ < 4; ++n_)
                bfr[n_] = *(const bf16x8*)&Bs[wc * 64 + n_ * 16 + rr][koff];
            #pragma unroll
            for (int m_ = 0; m_ < 4; ++m_)
                #pragma unroll
                for (int n_ = 0; n_ < 4; ++n_)
                    G.acc[m_][n_] = __builtin_amdgcn_mfma_f32_16x16x32_bf16(
                        af[m_], bfr[n_], G.acc[m_][n_], 0, 0, 0);
        }
        __syncthreads();
    }
}

// Fused Q/K/V projection: grid (M/128, 24); blockIdx.y>>3 selects section.
__global__ __launch_bounds__(256, 2)
void gemm_qkv(const short* __restrict__ A,
              const short* __restrict__ Wq, const short* __restrict__ Wk,
              const short* __restrict__ Wv,
              const float* __restrict__ bq, const float* __restrict__ bk,
              const float* __restrict__ bv,
              short* __restrict__ Qo, short* __restrict__ Ko, short* __restrict__ Vto,
              float sq)
{
    __shared__ __align__(16) short As[128][64];
    __shared__ __align__(16) short Bs[128][64];
    const int sec = blockIdx.y >> 3;
    const int bn = (blockIdx.y & 7) * 128;
    const int bm = blockIdx.x * 128;
    const short* Bw = sec == 0 ? Wq : sec == 1 ? Wk : Wv;
    const float* bias = sec == 0 ? bq : sec == 1 ? bk : bv;
    const float scale = sec == 0 ? sq : 1.0f;

    GemmAcc G = {};
    gemm_core(A, Bw, Cc, bm, bn, threadIdx.x, As, Bs, G);

    const int lane = threadIdx.x & 63, wid = threadIdx.x >> 6;
    const int wr = wid >> 1, wc = wid & 1;
    const int cidx = lane & 15;
    const int r4 = (lane >> 4) * 4;
    #pragma unroll
    for (int n_ = 0; n_ < 4; ++n_) {
        const int col = bn + wc * 64 + n_ * 16 + cidx;
        const float bv_ = bias[col];
        #pragma unroll
        for (int m_ = 0; m_ < 4; ++m_) {
            const int rowb = bm + wr * 64 + m_ * 16 + r4;
            if (sec == 2) {
                // transposed V: Vt[((b*16+h)*64 + d)][t]
                const int h_ = col >> 6, d_ = col & 63;
                const int b_ = rowb >> 11, t_ = rowb & 2047;
                short tmp[4];
                #pragma unroll
                for (int i = 0; i < 4; ++i) tmp[i] = f2bf((G.acc[m_][n_][i] + bv_));
                *(bf16x4*)(Vto + ((size_t)((b_ * Hh + h_) * HDd + d_)) * Tt + t_) = *(bf16x4*)tmp;
            } else {
                short* C = sec == 0 ? Qo : Ko;
                #pragma unroll
                for (int i = 0; i < 4; ++i)
                    C[(size_t)(rowb + i) * Cc + col] = f2bf((G.acc[m_][n_][i] + bv_) * scale);
            }
        }
    }
}

// Output projection: fp32 out.
__global__ __launch_bounds__(256, 2)
void gemm_out(const short* __restrict__ A, const short* __restrict__ Bw,
              const float* __restrict__ bias, float* __restrict__ Cout)
{
    __shared__ __align__(16) short As[128][64];
    __shared__ __align__(16) short Bs[128][64];
    const int bm = blockIdx.x * 128;
    const int bn = blockIdx.y * 128;
    GemmAcc G = {};
    gemm_core(A, Bw, Cc, bm, bn, threadIdx.x, As, Bs, G);

    const int lane = threadIdx.x & 63, wid = threadIdx.x >> 6;
    const int wr = wid >> 1, wc = wid & 1;
    const int cidx = lane & 15;
    const int r4 = (lane >> 4) * 4;
    #pragma unroll
    for (int n_ = 0; n_ < 4; ++n_) {
        const int col = bn + wc * 64 + n_ * 16 + cidx;
        const float bv_ = bias[col];
        #pragma unroll
        for (int m_ = 0; m_ < 4; ++m_) {
            const int rowb = bm + wr * 64 + m_ * 16 + r4;
            #pragma unroll
            for (int i = 0; i < 4; ++i)
                Cout[(size_t)(rowb + i) * Cc + col] = G.acc[m_][n_][i] + bv_;
        }
    }
}

// ---------------- Flash attention (causal, 32x32 MFMA, in-register P) ----------------
// 4 waves x 32 q-rows = QBLK 128; KVBLK 64. Swapped QK: mfma(K,Q) -> lane holds
// S[kv = kv0 + nb*32 + (r&3)+8*(r>>2)+4*hi][q = lane&31].
template<bool DIAG>
DEVI void attn_tile(int kv0, const short (*Kt)[64], const short (*Vd)[64],
                    const bf16x8 (&qf)[4], int lane, int qrow,
                    f32x16 (&oacc)[2], float &mrow, float &lsum)
{
    const int q31 = lane & 31;
    const int hi  = lane >> 5;

    f32x16 sacc[2] = {};
    __builtin_amdgcn_s_setprio(1);
    #pragma unroll
    for (int ks = 0; ks < 4; ++ks) {
        #pragma unroll
        for (int nb = 0; nb < 2; ++nb) {
            const int row = nb * 32 + q31;  // A-operand row = kv
            bf16x8 kf = *(const bf16x8*)&Kt[row][(((ks << 1) | hi) ^ (row & 7)) * 8];
            sacc[nb] = __builtin_amdgcn_mfma_f32_32x32x16_bf16(kf, qf[ks], sacc[nb], 0, 0, 0);
        }
    }
    __builtin_amdgcn_s_setprio(0);

    if (DIAG) {
        #pragma unroll
        for (int nb = 0; nb < 2; ++nb)
            #pragma unroll
            for (int r = 0; r < 16; ++r) {
                const int kv = kv0 + nb * 32 + (r & 3) + 8 * (r >> 2) + 4 * hi;
                if (kv > qrow) sacc[nb][r] = -1e30f;
            }
    }

    // row max: pairwise tree, depth 5, then one cross-half swap
    float tm[16];
    #pragma unroll
    for (int r = 0; r < 16; ++r) tm[r] = fmaxf(sacc[0][r], sacc[1][r]);
    #pragma unroll
    for (int st = 8; st >= 1; st >>= 1)
        #pragma unroll
        for (int r = 0; r < st; ++r) tm[r] = fmaxf(tm[r], tm[r + st]);
    const float pmax = fmaxf(tm[0], __shfl_xor(tm[0], 32, 64));

    if (!__all(pmax <= mrow + 8.0f)) {          // defer-max: rescale rarely
        const float mnew = fmaxf(mrow, pmax);
        const float alpha = fexp2(mrow - mnew);
        mrow = mnew;
        lsum *= alpha;
        #pragma unroll
        for (int r = 0; r < 16; ++r) {
            const float ar = __shfl(alpha, (r & 3) + 8 * (r >> 2) + 4 * hi, 32);
            oacc[0][r] *= ar;
            oacc[1][r] *= ar;
        }
    }

    // exp2 (raw v_exp_f32), then pairwise tree sum, single accumulate into lsum
    #pragma unroll
    for (int nb = 0; nb < 2; ++nb)
        #pragma unroll
        for (int r = 0; r < 16; ++r)
            sacc[nb][r] = fexp2(sacc[nb][r] - mrow);
    float ps[16];
    #pragma unroll
    for (int r = 0; r < 16; ++r) ps[r] = sacc[0][r] + sacc[1][r];
    #pragma unroll
    for (int st = 8; st >= 1; st >>= 1)
        #pragma unroll
        for (int r = 0; r < st; ++r) ps[r] += ps[r + st];
    lsum += ps[0];

    // PV with in-register P (cvt_pk + permlane32_swap), register-level bit_cast
    #pragma unroll
    for (int ks = 0; ks < 4; ++ks) {
        const int n = ks >> 1, b8 = (ks & 1) * 8;
        int x0 = cvtpk(sacc[n][b8 + 0], sacc[n][b8 + 1]);
        int x1 = cvtpk(sacc[n][b8 + 2], sacc[n][b8 + 3]);
        int y0 = cvtpk(sacc[n][b8 + 4], sacc[n][b8 + 5]);
        int y1 = cvtpk(sacc[n][b8 + 6], sacc[n][b8 + 7]);
        asm volatile("v_permlane32_swap_b32 %0, %1" : "+v"(x0), "+v"(y0));
        asm volatile("v_permlane32_swap_b32 %0, %1" : "+v"(x1), "+v"(y1));
        i32x4 w; w.x = x0; w.y = x1; w.z = y0; w.w = y1;
        const bf16x8 pav = __builtin_bit_cast(bf16x8, w);
        __builtin_amdgcn_s_setprio(1);
        #pragma unroll
        for (int nb = 0; nb < 2; ++nb) {
            const int row = nb * 32 + q31;  // B-operand col = d
            bf16x8 vf = *(const bf16x8*)&Vd[row][(((ks << 1) | hi) ^ (row & 7)) * 8];
            oacc[nb] = __builtin_amdgcn_mfma_f32_32x32x16_bf16(pav, vf, oacc[nb], 0, 0, 0);
        }
        __builtin_amdgcn_s_setprio(0);
    }
}

// One full 128-row q-tile pass. 4 waves, each owns 32 q-rows; KV tiles of 64.
// TRIPLE-buffered staging: 2 tiles of prefetch in flight (steady-state
// vmcnt(8) = tile t+1's 4 + t+2's 4 loads outstanding; t guaranteed landed).
DEVI void attn_run(int qt, const short* __restrict__ Q, short* __restrict__ O,
                   const short* kbase, const short* vbase, size_t baseRow, int h,
                   int lane, int wid, short (*Kb)[64][64], short (*Vb)[64][64])
{
    const int q0 = qt * 128;
    const int q31 = lane & 31;
    const int hi = lane >> 5;
    const int qrow = q0 + wid * 32 + q31;

    const short* qptr = Q + (baseRow + qrow) * Cc + h * HDd + hi * 8;
    bf16x8 qf[4];
    #pragma unroll
    for (int ks = 0; ks < 4; ++ks) qf[ks] = *(const bf16x8*)(qptr + ks * 16);

    f32x16 oacc[2] = {};
    float mrow = -1e30f, lsum = 0.f;
    const int NT = 2 * qt + 2;   // always >= 2

    auto STAGE = [&](int bsel, int kv0) {
        #pragma unroll
        for (int j = 0; j < 2; ++j) {
            const int r0 = wid * 16 + j * 8;
            const int row = r0 + (lane >> 3);
            const int sc = ((lane & 7) ^ (row & 7)) * 8;   // source-side chunk swizzle
            gload_lds16(kbase + (size_t)(kv0 + row) * Cc + sc, &Kb[bsel][r0][0]);
            gload_lds16(vbase + (size_t)row * Tt + kv0 + sc, &Vb[bsel][r0][0]);
        }
    };

    STAGE(0, 0);
    STAGE(1, 64);
    for (int kt = 0; kt < NT; ++kt) {
        const int buf = kt % 3;
        if (kt + 2 < NT) {
            STAGE((kt + 2) % 3, (kt + 2) * 64);              // 2-deep prefetch
            asm volatile("s_waitcnt vmcnt(8)" ::: "memory"); // tile kt landed
        } else if (kt + 1 < NT) {
            asm volatile("s_waitcnt vmcnt(4)" ::: "memory");
        } else {
            asm volatile("s_waitcnt vmcnt(0)" ::: "memory");
        }
        __builtin_amdgcn_s_barrier();
        __builtin_amdgcn_sched_barrier(0);
        if (kt >= NT - 2)   // diagonal band spans the last two KV tiles
            attn_tile<true >(kt * 64, Kb[buf], Vb[buf], qf, lane, qrow, oacc, mrow, lsum);
        else
            attn_tile<false>(kt * 64, Kb[buf], Vb[buf], qf, lane, qrow, oacc, mrow, lsum);
        __builtin_amdgcn_s_barrier();   // safe to overwrite buf (kt-1)%3 next iter
    }

    // epilogue: lane-pair sum -> per-q totals; O row q = crow(r,hi), col d = nb*32+q31
    lsum += __shfl_xor(lsum, 32, 64);
    #pragma unroll
    for (int r = 0; r < 16; ++r) {
        const int crow = (r & 3) + 8 * (r >> 2) + 4 * hi;
        const float ri = __builtin_amdgcn_rcpf(__shfl(lsum, crow, 32));
        const size_t rb = (baseRow + q0 + wid * 32 + crow) * Cc + h * HDd + q31;
        O[rb]      = f2bf(oacc[0][r] * ri);
        O[rb + 32] = f2bf(oacc[1][r] * ri);
    }
}

// 1-D grid of 1024 single-q-tile blocks.
//   xcd-affinity: all blocks of a given bh share bid%8 -> same XCD L2 keeps
//   that bh's K/V (512 KB) resident (r11: FETCH 148 -> 30 MB).
//   LPT: qt = 15 - (bid>>6) -> longest blocks dispatch first, no makespan tail.
__global__ __launch_bounds__(256, 3)
void attn_kernel(const short* __restrict__ Q, const short* __restrict__ K,
                 const short* __restrict__ Vt, short* __restrict__ O)
{
    const int bid = blockIdx.x;
    const int bh = (bid & 7) + 8 * ((bid >> 3) & 7);
    const int qt = 15 - (bid >> 6);
    const int b = bh >> 4, h = bh & 15;
    const size_t baseRow = (size_t)b * Tt;
    const int tid = threadIdx.x, lane = tid & 63, wid = tid >> 6;

    __shared__ __align__(16) short Kb[3][64][64];
    __shared__ __align__(16) short Vb[3][64][64];

    const short* kbase = K + baseRow * Cc + h * HDd;
    const short* vbase = Vt + (size_t)bh * HDd * Tt;

    attn_run(qt, Q, O, kbase, vbase, baseRow, h, lane, wid, Kb, Vb);
}

// ---------------- host ----------------
extern "C" void kernel_launch(void* const* d_in, const int* in_sizes, int n_in,
                              void* d_out, int out_size, void* d_ws, size_t ws_size,
                              hipStream_t stream) {
    (void)in_sizes; (void)n_in; (void)out_size; (void)ws_size;
    const float* x  = (const float*)d_in[0];
    const float* Wq = (const float*)d_in[1];
    const float* bq = (const float*)d_in[2];
    const float* Wk = (const float*)d_in[3];
    const float* bk = (const float*)d_in[4];
    const float* Wv = (const float*)d_in[5];
    const float* bv = (const float*)d_in[6];
    const float* Wo = (const float*)d_in[7];
    const float* bo = (const float*)d_in[8];
    float* out = (float*)d_out;

    short* ws  = (short*)d_ws;
    short* xb  = ws;
    short* wqb = xb  + (size_t)Mm * Cc;
    short* wkb = wqb + (size_t)Cc * Cc;
    short* wvb = wkb + (size_t)Cc * Cc;
    short* wob = wvb + (size_t)Cc * Cc;
    short* Qb  = wob + (size_t)Cc * Cc;
    short* Kbg = Qb  + (size_t)Mm * Cc;
    short* Vtb = Kbg + (size_t)Mm * Cc;  // V written pre-transposed by the QKV GEMM
    short* Ob  = Vtb + (size_t)Mm * Cc;

    const int nx8 = Mm * Cc / 8;
    const int nw8 = Cc * Cc / 8;
    cvt_kernel<<<(nx8 + 255) / 256, 256, 0, stream>>>(x, xb, nx8);
    cvtw_kernel<<<dim3(nw8 / 256, 4), 256, 0, stream>>>(Wq, Wk, Wv, Wo, wqb, wkb, wvb, wob);

    const float SCL = 0.125f * 1.44269504088896f;  // 1/sqrt(HD) * log2(e), folded into Q
    gemm_qkv<<<dim3(Mm / 128, 24), 256, 0, stream>>>(xb, wqb, wkb, wvb, bq, bk, bv,
                                                     Qb, Kbg, Vtb, SCL);

    attn_kernel<<<dim3(Tt / 128 * Bb * Hh), 256, 0, stream>>>(Qb, Kbg, Vtb, Ob);

    gemm_out<<<dim3(Mm / 128, Cc / 128), 256, 0, stream>>>(Ob, wob, bo, out);
}

// Round 16
// 165.083 us; speedup vs baseline: 1.0593x; 1.0131x over previous
//
#include <hip/hip_runtime.h>
#include <hip/hip_bf16.h>

#define DEVI __device__ __forceinline__

typedef __attribute__((ext_vector_type(4))) float f32x4;
typedef __attribute__((ext_vector_type(16))) float f32x16;
typedef __attribute__((ext_vector_type(8))) short bf16x8;
typedef __attribute__((ext_vector_type(4))) short bf16x4;
typedef __attribute__((ext_vector_type(4))) int i32x4;

constexpr int Bb = 4, Tt = 2048, Cc = 1024, Hh = 16, HDd = 64;
constexpr int Mm = Bb * Tt; // 8192

// ---- bf16 helpers ----
DEVI short f2bf(float f) {
    union { float f; unsigned u; } x; x.f = f;
    unsigned r = x.u + 0x7FFFu + ((x.u >> 16) & 1u); // round-nearest-even
    return (short)(r >> 16);
}

DEVI int cvtpk(float lo, float hi) { // packs {bf16(lo), bf16(hi)}, lo in low 16
    int r;
    asm("v_cvt_pk_bf16_f32 %0, %1, %2" : "=v"(r) : "v"(lo), "v"(hi));
    return r;
}

// raw v_exp_f32 (library exp2f w/o fast-math is a ~6-inst guarded sequence)
DEVI float fexp2(float x) { return __builtin_amdgcn_exp2f(x); }

DEVI void gload_lds16(const void* g, void* l) {
    __builtin_amdgcn_global_load_lds(
        (const __attribute__((address_space(1))) unsigned int*)g,
        (__attribute__((address_space(3))) unsigned int*)l, 16, 0, 0);
}

// ---------------- fp32 -> bf16 conversion (x + all 4 weights, ONE launch) ----
// grid 6144: blocks 0..4095 convert x (8.4M elems); blocks 4096+ convert the
// four 1M-elem weights (512 blocks each). Branch is wave-uniform per block.
__global__ void cvt_all(const float* __restrict__ x,
                        const float* __restrict__ w0, const float* __restrict__ w1,
                        const float* __restrict__ w2, const float* __restrict__ w3,
                        short* __restrict__ dx,
                        short* __restrict__ d0, short* __restrict__ d1,
                        short* __restrict__ d2, short* __restrict__ d3) {
    const int bid = blockIdx.x;
    const float* s; short* d; int i;
    if (bid < 4096) {
        s = x; d = dx; i = bid * 256 + threadIdx.x;
    } else {
        const int wsel = (bid - 4096) >> 9;
        s = wsel == 0 ? w0 : wsel == 1 ? w1 : wsel == 2 ? w2 : w3;
        d = wsel == 0 ? d0 : wsel == 1 ? d1 : wsel == 2 ? d2 : d3;
        i = ((bid - 4096) & 511) * 256 + threadIdx.x;
    }
    const float4* sp = (const float4*)s;
    float4 a = sp[2 * (size_t)i], b = sp[2 * (size_t)i + 1];
    short tmp[8];
    tmp[0] = f2bf(a.x); tmp[1] = f2bf(a.y); tmp[2] = f2bf(a.z); tmp[3] = f2bf(a.w);
    tmp[4] = f2bf(b.x); tmp[5] = f2bf(b.y); tmp[6] = f2bf(b.z); tmp[7] = f2bf(b.w);
    *(bf16x8*)(d + 8 * (size_t)i) = *(bf16x8*)tmp;
}

// ---------------- GEMM core (128x128 tile, BK=64) ----------------
struct GemmAcc { f32x4 acc[4][4]; };

DEVI void gemm_core(const short* __restrict__ A, const short* __restrict__ Bw,
                    int Kdim, int bm, int bn, int tid,
                    short (*As)[64], short (*Bs)[64], GemmAcc& G)
{
    const int lane = tid & 63, wid = tid >> 6;
    const int wr = wid >> 1, wc = wid & 1;
    const int lrow = lane >> 3;
    const int lcol = (lane & 7) * 8;

    for (int k0 = 0; k0 < Kdim; k0 += 64) {
        #pragma unroll
        for (int c = 0; c < 4; ++c) {
            const int chunk = wid * 4 + c;
            const int row = chunk * 8 + lrow;
            gload_lds16(A  + (size_t)(bm + row) * Kdim + k0 + lcol, &As[chunk * 8][0]);
            gload_lds16(Bw + (size_t)(bn + row) * Kdim + k0 + lcol, &Bs[chunk * 8][0]);
        }
        __syncthreads();
        const int rr = lane & 15;
        #pragma unroll
        for (int kk = 0; kk < 64; kk += 32) {
            const int koff = kk + (lane >> 4) * 8;
            bf16x8 af[4], bfr[4];
            #pragma unroll
            for (int m_ = 0; m_ < 4; ++m_)
                af[m_] = *(const bf16x8*)&As[wr * 64 + m_ * 16 + rr][koff];
            #pragma unroll
            for (int n_ = 0; n_ < 4; ++n_)
                bfr[n_] = *(const bf16x8*)&Bs[wc * 64 + n_ * 16 + rr][koff];
            #pragma unroll
            for (int m_ = 0; m_ < 4; ++m_)
                #pragma unroll
                for (int n_ = 0; n_ < 4; ++n_)
                    G.acc[m_][n_] = __builtin_amdgcn_mfma_f32_16x16x32_bf16(
                        af[m_], bfr[n_], G.acc[m_][n_], 0, 0, 0);
        }
        __syncthreads();
    }
}

// Fused Q/K/V projection: grid (M/128, 24); blockIdx.y>>3 selects section.
__global__ __launch_bounds__(256, 2)
void gemm_qkv(const short* __restrict__ A,
              const short* __restrict__ Wq, const short* __restrict__ Wk,
              const short* __restrict__ Wv,
              const float* __restrict__ bq, const float* __restrict__ bk,
              const float* __restrict__ bv,
              short* __restrict__ Qo, short* __restrict__ Ko, short* __restrict__ Vto,
              float sq)
{
    __shared__ __align__(16) short As[128][64];
    __shared__ __align__(16) short Bs[128][64];
    const int sec = blockIdx.y >> 3;
    const int bn = (blockIdx.y & 7) * 128;
    const int bm = blockIdx.x * 128;
    const short* Bw = sec == 0 ? Wq : sec == 1 ? Wk : Wv;
    const float* bias = sec == 0 ? bq : sec == 1 ? bk : bv;
    const float scale = sec == 0 ? sq : 1.0f;

    GemmAcc G = {};
    gemm_core(A, Bw, Cc, bm, bn, threadIdx.x, As, Bs, G);

    const int lane = threadIdx.x & 63, wid = threadIdx.x >> 6;
    const int wr = wid >> 1, wc = wid & 1;
    const int cidx = lane & 15;
    const int r4 = (lane >> 4) * 4;
    #pragma unroll
    for (int n_ = 0; n_ < 4; ++n_) {
        const int col = bn + wc * 64 + n_ * 16 + cidx;
        const float bv_ = bias[col];
        #pragma unroll
        for (int m_ = 0; m_ < 4; ++m_) {
            const int rowb = bm + wr * 64 + m_ * 16 + r4;
            if (sec == 2) {
                // transposed V: Vt[((b*16+h)*64 + d)][t]
                const int h_ = col >> 6, d_ = col & 63;
                const int b_ = rowb >> 11, t_ = rowb & 2047;
                short tmp[4];
                #pragma unroll
                for (int i = 0; i < 4; ++i) tmp[i] = f2bf((G.acc[m_][n_][i] + bv_));
                *(bf16x4*)(Vto + ((size_t)((b_ * Hh + h_) * HDd + d_)) * Tt + t_) = *(bf16x4*)tmp;
            } else {
                short* C = sec == 0 ? Qo : Ko;
                #pragma unroll
                for (int i = 0; i < 4; ++i)
                    C[(size_t)(rowb + i) * Cc + col] = f2bf((G.acc[m_][n_][i] + bv_) * scale);
            }
        }
    }
}

// Output projection: fp32 out.
__global__ __launch_bounds__(256, 2)
void gemm_out(const short* __restrict__ A, const short* __restrict__ Bw,
              const float* __restrict__ bias, float* __restrict__ Cout)
{
    __shared__ __align__(16) short As[128][64];
    __shared__ __align__(16) short Bs[128][64];
    const int bm = blockIdx.x * 128;
    const int bn = blockIdx.y * 128;
    GemmAcc G = {};
    gemm_core(A, Bw, Cc, bm, bn, threadIdx.x, As, Bs, G);

    const int lane = threadIdx.x & 63, wid = threadIdx.x >> 6;
    const int wr = wid >> 1, wc = wid & 1;
    const int cidx = lane & 15;
    const int r4 = (lane >> 4) * 4;
    #pragma unroll
    for (int n_ = 0; n_ < 4; ++n_) {
        const int col = bn + wc * 64 + n_ * 16 + cidx;
        const float bv_ = bias[col];
        #pragma unroll
        for (int m_ = 0; m_ < 4; ++m_) {
            const int rowb = bm + wr * 64 + m_ * 16 + r4;
            #pragma unroll
            for (int i = 0; i < 4; ++i)
                Cout[(size_t)(rowb + i) * Cc + col] = G.acc[m_][n_][i] + bv_;
        }
    }
}

// ---------------- Flash attention (causal, 32x32 MFMA, in-register P) ----------------
// 4 waves x 32 q-rows = QBLK 128; KVBLK 64. Swapped QK: mfma(K,Q) -> lane holds
// S[kv = kv0 + nb*32 + (r&3)+8*(r>>2)+4*hi][q = lane&31].
template<bool DIAG>
DEVI void attn_tile(int kv0, const short (*Kt)[64], const short (*Vd)[64],
                    const bf16x8 (&qf)[4], int lane, int qrow,
                    f32x16 (&oacc)[2], float &mrow, float &lsum)
{
    const int q31 = lane & 31;
    const int hi  = lane >> 5;

    f32x16 sacc[2] = {};
    __builtin_amdgcn_s_setprio(1);
    #pragma unroll
    for (int ks = 0; ks < 4; ++ks) {
        #pragma unroll
        for (int nb = 0; nb < 2; ++nb) {
            const int row = nb * 32 + q31;  // A-operand row = kv
            bf16x8 kf = *(const bf16x8*)&Kt[row][(((ks << 1) | hi) ^ (row & 7)) * 8];
            sacc[nb] = __builtin_amdgcn_mfma_f32_32x32x16_bf16(kf, qf[ks], sacc[nb], 0, 0, 0);
        }
    }
    __builtin_amdgcn_s_setprio(0);

    if (DIAG) {
        #pragma unroll
        for (int nb = 0; nb < 2; ++nb)
            #pragma unroll
            for (int r = 0; r < 16; ++r) {
                const int kv = kv0 + nb * 32 + (r & 3) + 8 * (r >> 2) + 4 * hi;
                if (kv > qrow) sacc[nb][r] = -1e30f;
            }
    }

    // row max: pairwise tree, depth 5, then one cross-half swap
    float tm[16];
    #pragma unroll
    for (int r = 0; r < 16; ++r) tm[r] = fmaxf(sacc[0][r], sacc[1][r]);
    #pragma unroll
    for (int st = 8; st >= 1; st >>= 1)
        #pragma unroll
        for (int r = 0; r < st; ++r) tm[r] = fmaxf(tm[r], tm[r + st]);
    const float pmax = fmaxf(tm[0], __shfl_xor(tm[0], 32, 64));

    if (!__all(pmax <= mrow + 8.0f)) {          // defer-max: rescale rarely
        const float mnew = fmaxf(mrow, pmax);
        const float alpha = fexp2(mrow - mnew);
        mrow = mnew;
        lsum *= alpha;
        #pragma unroll
        for (int r = 0; r < 16; ++r) {
            const float ar = __shfl(alpha, (r & 3) + 8 * (r >> 2) + 4 * hi, 32);
            oacc[0][r] *= ar;
            oacc[1][r] *= ar;
        }
    }

    // exp2 (raw v_exp_f32), then pairwise tree sum, single accumulate into lsum
    #pragma unroll
    for (int nb = 0; nb < 2; ++nb)
        #pragma unroll
        for (int r = 0; r < 16; ++r)
            sacc[nb][r] = fexp2(sacc[nb][r] - mrow);
    float ps[16];
    #pragma unroll
    for (int r = 0; r < 16; ++r) ps[r] = sacc[0][r] + sacc[1][r];
    #pragma unroll
    for (int st = 8; st >= 1; st >>= 1)
        #pragma unroll
        for (int r = 0; r < st; ++r) ps[r] += ps[r + st];
    lsum += ps[0];

    // PV with in-register P (cvt_pk + permlane32_swap), register-level bit_cast
    #pragma unroll
    for (int ks = 0; ks < 4; ++ks) {
        const int n = ks >> 1, b8 = (ks & 1) * 8;
        int x0 = cvtpk(sacc[n][b8 + 0], sacc[n][b8 + 1]);
        int x1 = cvtpk(sacc[n][b8 + 2], sacc[n][b8 + 3]);
        int y0 = cvtpk(sacc[n][b8 + 4], sacc[n][b8 + 5]);
        int y1 = cvtpk(sacc[n][b8 + 6], sacc[n][b8 + 7]);
        asm volatile("v_permlane32_swap_b32 %0, %1" : "+v"(x0), "+v"(y0));
        asm volatile("v_permlane32_swap_b32 %0, %1" : "+v"(x1), "+v"(y1));
        i32x4 w; w.x = x0; w.y = x1; w.z = y0; w.w = y1;
        const bf16x8 pav = __builtin_bit_cast(bf16x8, w);
        __builtin_amdgcn_s_setprio(1);
        #pragma unroll
        for (int nb = 0; nb < 2; ++nb) {
            const int row = nb * 32 + q31;  // B-operand col = d
            bf16x8 vf = *(const bf16x8*)&Vd[row][(((ks << 1) | hi) ^ (row & 7)) * 8];
            oacc[nb] = __builtin_amdgcn_mfma_f32_32x32x16_bf16(pav, vf, oacc[nb], 0, 0, 0);
        }
        __builtin_amdgcn_s_setprio(0);
    }
}

// One full 128-row q-tile pass. 4 waves, each owns 32 q-rows; KV tiles of 64.
// Double-buffered staging, counted vmcnt(4) (r13 best-measured config).
DEVI void attn_run(int qt, const short* __restrict__ Q, short* __restrict__ O,
                   const short* kbase, const short* vbase, size_t baseRow, int h,
                   int lane, int wid, short (*Kb)[64][64], short (*Vb)[64][64])
{
    const int q0 = qt * 128;
    const int q31 = lane & 31;
    const int hi = lane >> 5;
    const int qrow = q0 + wid * 32 + q31;

    const short* qptr = Q + (baseRow + qrow) * Cc + h * HDd + hi * 8;
    bf16x8 qf[4];
    #pragma unroll
    for (int ks = 0; ks < 4; ++ks) qf[ks] = *(const bf16x8*)(qptr + ks * 16);

    f32x16 oacc[2] = {};
    float mrow = -1e30f, lsum = 0.f;
    const int NT = 2 * qt + 2;

    auto STAGE = [&](int bsel, int kv0) {
        #pragma unroll
        for (int j = 0; j < 2; ++j) {
            const int r0 = wid * 16 + j * 8;
            const int row = r0 + (lane >> 3);
            const int sc = ((lane & 7) ^ (row & 7)) * 8;   // source-side chunk swizzle
            gload_lds16(kbase + (size_t)(kv0 + row) * Cc + sc, &Kb[bsel][r0][0]);
            gload_lds16(vbase + (size_t)row * Tt + kv0 + sc, &Vb[bsel][r0][0]);
        }
    };

    STAGE(0, 0);
    int buf = 0;
    for (int kt = 0; kt < NT; ++kt) {
        if (kt + 1 < NT) {
            STAGE(buf ^ 1, (kt + 1) * 64);                   // +4 in flight (8 total)
            asm volatile("s_waitcnt vmcnt(4)" ::: "memory"); // current tile landed
        } else {
            asm volatile("s_waitcnt vmcnt(0)" ::: "memory");
        }
        __builtin_amdgcn_s_barrier();
        __builtin_amdgcn_sched_barrier(0);
        if (kt >= NT - 2)   // diagonal band spans the last two KV tiles
            attn_tile<true >(kt * 64, Kb[buf], Vb[buf], qf, lane, qrow, oacc, mrow, lsum);
        else
            attn_tile<false>(kt * 64, Kb[buf], Vb[buf], qf, lane, qrow, oacc, mrow, lsum);
        __builtin_amdgcn_s_barrier();
        buf ^= 1;
    }

    // epilogue: lane-pair sum -> per-q totals; O row q = crow(r,hi), col d = nb*32+q31
    lsum += __shfl_xor(lsum, 32, 64);
    #pragma unroll
    for (int r = 0; r < 16; ++r) {
        const int crow = (r & 3) + 8 * (r >> 2) + 4 * hi;
        const float ri = __builtin_amdgcn_rcpf(__shfl(lsum, crow, 32));
        const size_t rb = (baseRow + q0 + wid * 32 + crow) * Cc + h * HDd + q31;
        O[rb]      = f2bf(oacc[0][r] * ri);
        O[rb + 32] = f2bf(oacc[1][r] * ri);
    }
}

// 1-D grid of 1024 single-q-tile blocks.
//   xcd-affinity: all blocks of a given bh share bid%8 -> same XCD L2 keeps
//   that bh's K/V (512 KB) resident (r11: FETCH 148 -> 30 MB).
//   LPT: qt = 15 - (bid>>6) -> longest blocks dispatch first, no makespan tail.
__global__ __launch_bounds__(256, 3)
void attn_kernel(const short* __restrict__ Q, const short* __restrict__ K,
                 const short* __restrict__ Vt, short* __restrict__ O)
{
    const int bid = blockIdx.x;
    const int bh = (bid & 7) + 8 * ((bid >> 3) & 7);
    const int qt = 15 - (bid >> 6);
    const int b = bh >> 4, h = bh & 15;
    const size_t baseRow = (size_t)b * Tt;
    const int tid = threadIdx.x, lane = tid & 63, wid = tid >> 6;

    __shared__ __align__(16) short Kb[2][64][64];
    __shared__ __align__(16) short Vb[2][64][64];

    const short* kbase = K + baseRow * Cc + h * HDd;
    const short* vbase = Vt + (size_t)bh * HDd * Tt;

    attn_run(qt, Q, O, kbase, vbase, baseRow, h, lane, wid, Kb, Vb);
}

// ---------------- host ----------------
extern "C" void kernel_launch(void* const* d_in, const int* in_sizes, int n_in,
                              void* d_out, int out_size, void* d_ws, size_t ws_size,
                              hipStream_t stream) {
    (void)in_sizes; (void)n_in; (void)out_size; (void)ws_size;
    const float* x  = (const float*)d_in[0];
    const float* Wq = (const float*)d_in[1];
    const float* bq = (const float*)d_in[2];
    const float* Wk = (const float*)d_in[3];
    const float* bk = (const float*)d_in[4];
    const float* Wv = (const float*)d_in[5];
    const float* bv = (const float*)d_in[6];
    const float* Wo = (const float*)d_in[7];
    const float* bo = (const float*)d_in[8];
    float* out = (float*)d_out;

    short* ws  = (short*)d_ws;
    short* xb  = ws;
    short* wqb = xb  + (size_t)Mm * Cc;
    short* wkb = wqb + (size_t)Cc * Cc;
    short* wvb = wkb + (size_t)Cc * Cc;
    short* wob = wvb + (size_t)Cc * Cc;
    short* Qb  = wob + (size_t)Cc * Cc;
    short* Kbg = Qb  + (size_t)Mm * Cc;
    short* Vtb = Kbg + (size_t)Mm * Cc;  // V written pre-transposed by the QKV GEMM
    short* Ob  = Vtb + (size_t)Mm * Cc;

    // single fused conversion launch: x (4096 blocks) + 4 weights (4*512)
    cvt_all<<<dim3(4096 + 4 * 512), 256, 0, stream>>>(x, Wq, Wk, Wv, Wo,
                                                      xb, wqb, wkb, wvb, wob);

    const float SCL = 0.125f * 1.44269504088896f;  // 1/sqrt(HD) * log2(e), folded into Q
    gemm_qkv<<<dim3(Mm / 128, 24), 256, 0, stream>>>(xb, wqb, wkb, wvb, bq, bk, bv,
                                                     Qb, Kbg, Vtb, SCL);

    attn_kernel<<<dim3(Tt / 128 * Bb * Hh), 256, 0, stream>>>(Qb, Kbg, Vtb, Ob);

    gemm_out<<<dim3(Mm / 128, Cc / 128), 256, 0, stream>>>(Ob, wob, bo, out);
}